// Round 10
// baseline (51.869 us; speedup 1.0000x reference)
//
#include <hip/hip_runtime.h>

#define MAXLEN 768
#define DMODEL 512
// conv output length T = MAXLEN - KSIZE + 1 = 766

typedef float f32x4 __attribute__((ext_vector_type(4)));

// Fused: one wave per row. Predicated CACHED prefix reads (touched ~105 MiB of
// x stays L3-resident across graph replays). Stores are now also CACHED:
// out (128 MiB) + touched x (~105 MiB) = 233 MiB < 256 MiB Infinity Cache, so
// out's lines stay dirty-resident and replays rewrite them in L3 instead of
// streaming 134 MB to HBM every replay (which nt stores forced).
__global__ __launch_bounds__(256) void patch_embed_kernel(
    const float* __restrict__ x,
    const int*   __restrict__ lengths,
    const float* __restrict__ w,   // [DMODEL][3] row-major
    const float* __restrict__ b,   // [DMODEL]
    float*       __restrict__ out, // [N][DMODEL]
    int n_rows)
{
    const int lane = threadIdx.x & 63;
    const int row  = (int)((blockIdx.x * blockDim.x + threadIdx.x) >> 6);
    if (row >= n_rows) return;

    const int L = lengths[row];
    const float* xr = x + (size_t)row * MAXLEN + 4 * lane;

    f32x4 va = {0.f, 0.f, 0.f, 0.f};
    f32x4 vb = {0.f, 0.f, 0.f, 0.f};
    f32x4 vc = {0.f, 0.f, 0.f, 0.f};
    // predicated cached loads: only fetch vectors intersecting the valid prefix
    if (4 * lane < L)
        va = *reinterpret_cast<const f32x4*>(xr);
    if (4 * lane + 256 < L)
        vb = *reinterpret_cast<const f32x4*>(xr + 256);
    if (4 * lane + 512 < L)
        vc = *reinterpret_cast<const f32x4*>(xr + 512);

    // weight/bias loads: tiny, L1-hot
    const int d0 = 4 * lane;
    const int d1 = 4 * lane + 256;
    const f32x4 wa0 = *reinterpret_cast<const f32x4*>(w + 3 * d0 + 0);
    const f32x4 wb0 = *reinterpret_cast<const f32x4*>(w + 3 * d0 + 4);
    const f32x4 wc0 = *reinterpret_cast<const f32x4*>(w + 3 * d0 + 8);
    const f32x4 bb0 = *reinterpret_cast<const f32x4*>(b + d0);
    const f32x4 wa1 = *reinterpret_cast<const f32x4*>(w + 3 * d1 + 0);
    const f32x4 wb1 = *reinterpret_cast<const f32x4*>(w + 3 * d1 + 4);
    const f32x4 wc1 = *reinterpret_cast<const f32x4*>(w + 3 * d1 + 8);
    const f32x4 bb1 = *reinterpret_cast<const f32x4*>(b + d1);

    float e0 = 0.0f, e1 = 0.0f, e766 = 0.0f, e767 = 0.0f;
    float sa, sb, sc;
    {
        const int p = 4 * lane;
        const float v0 = (p + 0 < L) ? va.x : 0.0f;
        const float v1 = (p + 1 < L) ? va.y : 0.0f;
        const float v2 = (p + 2 < L) ? va.z : 0.0f;
        const float v3 = (p + 3 < L) ? va.w : 0.0f;
        sa = (v0 + v1) + (v2 + v3);
        e0 = v0; e1 = v1;                       // valid on lane 0 (L >= 3 always)
    }
    {
        const int p = 4 * lane + 256;
        const float v0 = (p + 0 < L) ? vb.x : 0.0f;
        const float v1 = (p + 1 < L) ? vb.y : 0.0f;
        const float v2 = (p + 2 < L) ? vb.z : 0.0f;
        const float v3 = (p + 3 < L) ? vb.w : 0.0f;
        sb = (v0 + v1) + (v2 + v3);
    }
    {
        const int p = 4 * lane + 512;
        const float v0 = (p + 0 < L) ? vc.x : 0.0f;
        const float v1 = (p + 1 < L) ? vc.y : 0.0f;
        const float v2 = (p + 2 < L) ? vc.z : 0.0f;
        const float v3 = (p + 3 < L) ? vc.w : 0.0f;
        sc = (v0 + v1) + (v2 + v3);
        e766 = v2; e767 = v3;                   // valid on lane 63 (0 if L<=766)
    }
    float s = (sa + sb) + sc;

#pragma unroll
    for (int off = 32; off > 0; off >>= 1)
        s += __shfl_xor(s, off, 64);
    e0   = __shfl(e0, 0, 64);
    e1   = __shfl(e1, 0, 64);
    e766 = __shfl(e766, 63, 64);
    e767 = __shfl(e767, 63, 64);

    const float inv = 1.0f / 766.0f;
    const float m0 = (s - e766 - e767) * inv;
    const float m1 = (s - e0 - e767) * inv;
    const float m2 = (s - e0 - e1) * inv;

    float* orow = out + (size_t)row * DMODEL;
    f32x4 o0, o1;
    o0.x = bb0.x + m0 * wa0.x + m1 * wa0.y + m2 * wa0.z;
    o0.y = bb0.y + m0 * wa0.w + m1 * wb0.x + m2 * wb0.y;
    o0.z = bb0.z + m0 * wb0.z + m1 * wb0.w + m2 * wc0.x;
    o0.w = bb0.w + m0 * wc0.y + m1 * wc0.z + m2 * wc0.w;
    o1.x = bb1.x + m0 * wa1.x + m1 * wa1.y + m2 * wa1.z;
    o1.y = bb1.y + m0 * wa1.w + m1 * wb1.x + m2 * wb1.y;
    o1.z = bb1.z + m0 * wb1.z + m1 * wb1.w + m2 * wc1.x;
    o1.w = bb1.w + m0 * wc1.y + m1 * wc1.z + m2 * wc1.w;
    *reinterpret_cast<f32x4*>(orow + d0) = o0;   // cached write-back stores
    *reinterpret_cast<f32x4*>(orow + d1) = o1;
}

extern "C" void kernel_launch(void* const* d_in, const int* in_sizes, int n_in,
                              void* d_out, int out_size, void* d_ws, size_t ws_size,
                              hipStream_t stream) {
    const float* x       = (const float*)d_in[0];
    const int*   lengths = (const int*)  d_in[1];
    const float* conv_w  = (const float*)d_in[2];
    const float* conv_b  = (const float*)d_in[3];
    float* out = (float*)d_out;

    const int n_rows = in_sizes[1];               // 65536
    const int grid = (n_rows + 3) / 4;            // 4 waves/block, 1 row/wave

    patch_embed_kernel<<<grid, 256, 0, stream>>>(x, lengths, conv_w, conv_b, out, n_rows);
}

// Round 11
// 40.155 us; speedup vs baseline: 1.2917x; 1.2917x over previous
//
#include <hip/hip_runtime.h>

#define MAXLEN 768
#define DMODEL 512
// conv output length T = MAXLEN - KSIZE + 1 = 766

typedef float f32x4 __attribute__((ext_vector_type(4)));

// FINAL (R8 structure): fused, one wave per row.
//  - Predicated CACHED prefix reads: positions >= lengths[row] contribute 0 and
//    are never fetched; the touched ~105 MiB of x stays L3-resident across
//    graph replays (nt loads forfeited this: R7 = +10 us).
//  - NONTEMPORAL stores: out is write-once; cached stores trigger
//    read-for-ownership (+134 MB fetch, R10 = +11.5 us).
//  - Fused beats split (R9): L3-served reads overlap the HBM write stream.
__global__ __launch_bounds__(256) void patch_embed_kernel(
    const float* __restrict__ x,
    const int*   __restrict__ lengths,
    const float* __restrict__ w,   // [DMODEL][3] row-major
    const float* __restrict__ b,   // [DMODEL]
    float*       __restrict__ out, // [N][DMODEL]
    int n_rows)
{
    const int lane = threadIdx.x & 63;
    const int row  = (int)((blockIdx.x * blockDim.x + threadIdx.x) >> 6);
    if (row >= n_rows) return;

    const int L = lengths[row];
    const float* xr = x + (size_t)row * MAXLEN + 4 * lane;

    f32x4 va = {0.f, 0.f, 0.f, 0.f};
    f32x4 vb = {0.f, 0.f, 0.f, 0.f};
    f32x4 vc = {0.f, 0.f, 0.f, 0.f};
    // predicated cached loads: only fetch vectors intersecting the valid prefix
    if (4 * lane < L)
        va = *reinterpret_cast<const f32x4*>(xr);
    if (4 * lane + 256 < L)
        vb = *reinterpret_cast<const f32x4*>(xr + 256);
    if (4 * lane + 512 < L)
        vc = *reinterpret_cast<const f32x4*>(xr + 512);

    // weight/bias loads: tiny, L1-hot
    const int d0 = 4 * lane;
    const int d1 = 4 * lane + 256;
    const f32x4 wa0 = *reinterpret_cast<const f32x4*>(w + 3 * d0 + 0);
    const f32x4 wb0 = *reinterpret_cast<const f32x4*>(w + 3 * d0 + 4);
    const f32x4 wc0 = *reinterpret_cast<const f32x4*>(w + 3 * d0 + 8);
    const f32x4 bb0 = *reinterpret_cast<const f32x4*>(b + d0);
    const f32x4 wa1 = *reinterpret_cast<const f32x4*>(w + 3 * d1 + 0);
    const f32x4 wb1 = *reinterpret_cast<const f32x4*>(w + 3 * d1 + 4);
    const f32x4 wc1 = *reinterpret_cast<const f32x4*>(w + 3 * d1 + 8);
    const f32x4 bb1 = *reinterpret_cast<const f32x4*>(b + d1);

    float e0 = 0.0f, e1 = 0.0f, e766 = 0.0f, e767 = 0.0f;
    float sa, sb, sc;
    {
        const int p = 4 * lane;
        const float v0 = (p + 0 < L) ? va.x : 0.0f;
        const float v1 = (p + 1 < L) ? va.y : 0.0f;
        const float v2 = (p + 2 < L) ? va.z : 0.0f;
        const float v3 = (p + 3 < L) ? va.w : 0.0f;
        sa = (v0 + v1) + (v2 + v3);
        e0 = v0; e1 = v1;                       // valid on lane 0 (L >= 3 always)
    }
    {
        const int p = 4 * lane + 256;
        const float v0 = (p + 0 < L) ? vb.x : 0.0f;
        const float v1 = (p + 1 < L) ? vb.y : 0.0f;
        const float v2 = (p + 2 < L) ? vb.z : 0.0f;
        const float v3 = (p + 3 < L) ? vb.w : 0.0f;
        sb = (v0 + v1) + (v2 + v3);
    }
    {
        const int p = 4 * lane + 512;
        const float v0 = (p + 0 < L) ? vc.x : 0.0f;
        const float v1 = (p + 1 < L) ? vc.y : 0.0f;
        const float v2 = (p + 2 < L) ? vc.z : 0.0f;
        const float v3 = (p + 3 < L) ? vc.w : 0.0f;
        sc = (v0 + v1) + (v2 + v3);
        e766 = v2; e767 = v3;                   // valid on lane 63 (0 if L<=766)
    }
    float s = (sa + sb) + sc;

#pragma unroll
    for (int off = 32; off > 0; off >>= 1)
        s += __shfl_xor(s, off, 64);
    e0   = __shfl(e0, 0, 64);
    e1   = __shfl(e1, 0, 64);
    e766 = __shfl(e766, 63, 64);
    e767 = __shfl(e767, 63, 64);

    const float inv = 1.0f / 766.0f;
    const float m0 = (s - e766 - e767) * inv;
    const float m1 = (s - e0 - e767) * inv;
    const float m2 = (s - e0 - e1) * inv;

    float* orow = out + (size_t)row * DMODEL;
    f32x4 o0, o1;
    o0.x = bb0.x + m0 * wa0.x + m1 * wa0.y + m2 * wa0.z;
    o0.y = bb0.y + m0 * wa0.w + m1 * wb0.x + m2 * wb0.y;
    o0.z = bb0.z + m0 * wb0.z + m1 * wb0.w + m2 * wc0.x;
    o0.w = bb0.w + m0 * wc0.y + m1 * wc0.z + m2 * wc0.w;
    o1.x = bb1.x + m0 * wa1.x + m1 * wa1.y + m2 * wa1.z;
    o1.y = bb1.y + m0 * wa1.w + m1 * wb1.x + m2 * wb1.y;
    o1.z = bb1.z + m0 * wb1.z + m1 * wb1.w + m2 * wc1.x;
    o1.w = bb1.w + m0 * wc1.y + m1 * wc1.z + m2 * wc1.w;
    __builtin_nontemporal_store(o0, reinterpret_cast<f32x4*>(orow + d0));
    __builtin_nontemporal_store(o1, reinterpret_cast<f32x4*>(orow + d1));
}

extern "C" void kernel_launch(void* const* d_in, const int* in_sizes, int n_in,
                              void* d_out, int out_size, void* d_ws, size_t ws_size,
                              hipStream_t stream) {
    const float* x       = (const float*)d_in[0];
    const int*   lengths = (const int*)  d_in[1];
    const float* conv_w  = (const float*)d_in[2];
    const float* conv_b  = (const float*)d_in[3];
    float* out = (float*)d_out;

    const int n_rows = in_sizes[1];               // 65536
    const int grid = (n_rows + 3) / 4;            // 4 waves/block, 1 row/wave

    patch_embed_kernel<<<grid, 256, 0, stream>>>(x, lengths, conv_w, conv_b, out, n_rows);
}